// Round 4
// baseline (187.212 us; speedup 1.0000x reference)
//
#include <hip/hip_runtime.h>
#include <hip/hip_bf16.h>
#include <math.h>

#define HW 4096
#define NC 256
#define NB 8
#define NA 5
#define NIT 24
#define SCL 0.0625f

// workspace layout (float offsets).
// Region A (655360 floats) is reused three times, in stream order:
//   1) k_attnlog writes logit partials [ct2][sb16][a5][4096]
//   2) k_sinkhorn sums them, writes plan P [sb16][a5][4096] over the front
//   3) k_attn2log writes attn2 logit partials [ct2][ig2][b8][ii5][4096]
#define OFF_A     0
#define OFF_PROTO 655360                   // 2*8*256
#define OFF_QK    (OFF_PROTO + 4096)       // 2*8*5*256
#define OFF_PS    (OFF_QK + 20480)         // 2*8*5*256
#define OFF_W2    (OFF_PS + 20480)         // 8*10*4096
// total = 1,028,096 floats (4.11 MB)

__device__ inline float frcp(float x) { return __builtin_amdgcn_rcpf(x); }

// ---- DPP wave64 reductions: result valid in lane 63 ----
template<int NV>
__device__ inline void waveSum(float (&v)[NV]) {
    #pragma unroll
    for (int k = 0; k < NV; ++k) {
        float x = v[k]; int t;
        t = __builtin_amdgcn_update_dpp(0, __float_as_int(x), 0x111, 0xf, 0xf, true); x += __int_as_float(t);
        t = __builtin_amdgcn_update_dpp(0, __float_as_int(x), 0x112, 0xf, 0xf, true); x += __int_as_float(t);
        t = __builtin_amdgcn_update_dpp(0, __float_as_int(x), 0x114, 0xf, 0xf, true); x += __int_as_float(t);
        t = __builtin_amdgcn_update_dpp(0, __float_as_int(x), 0x118, 0xf, 0xf, true); x += __int_as_float(t);
        t = __builtin_amdgcn_update_dpp(0, __float_as_int(x), 0x142, 0xf, 0xf, true); x += __int_as_float(t);
        t = __builtin_amdgcn_update_dpp(0, __float_as_int(x), 0x143, 0xf, 0xf, true); x += __int_as_float(t);
        v[k] = x;
    }
}

template<int NV>
__device__ inline void waveMax(float (&v)[NV]) {
    #pragma unroll
    for (int k = 0; k < NV; ++k) {
        float x = v[k]; int t;
        t = __builtin_amdgcn_update_dpp(__float_as_int(x), __float_as_int(x), 0x111, 0xf, 0xf, false); x = fmaxf(x, __int_as_float(t));
        t = __builtin_amdgcn_update_dpp(__float_as_int(x), __float_as_int(x), 0x112, 0xf, 0xf, false); x = fmaxf(x, __int_as_float(t));
        t = __builtin_amdgcn_update_dpp(__float_as_int(x), __float_as_int(x), 0x114, 0xf, 0xf, false); x = fmaxf(x, __int_as_float(t));
        t = __builtin_amdgcn_update_dpp(__float_as_int(x), __float_as_int(x), 0x118, 0xf, 0xf, false); x = fmaxf(x, __int_as_float(t));
        t = __builtin_amdgcn_update_dpp(__float_as_int(x), __float_as_int(x), 0x142, 0xf, 0xf, false); x = fmaxf(x, __int_as_float(t));
        t = __builtin_amdgcn_update_dpp(__float_as_int(x), __float_as_int(x), 0x143, 0xf, 0xf, false); x = fmaxf(x, __int_as_float(t));
        v[k] = x;
    }
}

template<int NV>
__device__ inline void crossSum4(float (&v)[NV], float* buf, int lane, int wid) {
    waveSum<NV>(v);
    if (lane == 63) {
        #pragma unroll
        for (int k = 0; k < NV; ++k) buf[wid * NV + k] = v[k];
    }
    __syncthreads();
    #pragma unroll
    for (int k = 0; k < NV; ++k)
        v[k] = buf[k] + buf[NV + k] + buf[2 * NV + k] + buf[3 * NV + k];
}

template<int NV>
__device__ inline void crossMax4(float (&v)[NV], float* buf, int lane, int wid) {
    waveMax<NV>(v);
    if (lane == 63) {
        #pragma unroll
        for (int k = 0; k < NV; ++k) buf[wid * NV + k] = v[k];
    }
    __syncthreads();
    #pragma unroll
    for (int k = 0; k < NV; ++k)
        v[k] = fmaxf(fmaxf(buf[k], buf[NV + k]), fmaxf(buf[2 * NV + k], buf[3 * NV + k]));
}

// proto[s][b][c] = masked mean over HW (count computed inline)
__global__ __launch_bounds__(256) void k_proto(const float* __restrict__ f1, const float* __restrict__ f2,
                                               const int* __restrict__ m1, const int* __restrict__ m2,
                                               float* __restrict__ ws) {
    __shared__ float buf[8];
    int bid = blockIdx.x, tid = threadIdx.x;
    int lane = tid & 63, wid = tid >> 6;
    int s = bid >> 11, b = (bid >> 8) & 7, c = bid & 255;
    const float* f = s ? f2 : f1;
    const int* m = s ? m2 : m1;
    const float4* fb4 = (const float4*)(f + ((size_t)b * NC + c) * HW);
    const int4* mb4 = (const int4*)(m + b * HW);
    float v2[2] = {0.f, 0.f};
    #pragma unroll
    for (int j = 0; j < 4; ++j) {
        int idx = tid + j * 256;
        float4 v = fb4[idx];
        int4 mm = mb4[idx];
        if (mm.x == 1) { v2[0] += v.x; v2[1] += 1.f; }
        if (mm.y == 1) { v2[0] += v.y; v2[1] += 1.f; }
        if (mm.z == 1) { v2[0] += v.z; v2[1] += 1.f; }
        if (mm.w == 1) { v2[0] += v.w; v2[1] += 1.f; }
    }
    crossSum4<2>(v2, buf, lane, wid);
    if (tid == 0)
        ws[OFF_PROTO + (s * 8 + b) * NC + c] = v2[0] / (v2[1] + 1e-5f);
}

// fused: q = (proto+tok)@Wq^T ; qk = q@Wk
__global__ __launch_bounds__(256) void k_qk(const float* __restrict__ Wq, const float* __restrict__ Wk,
                                            const float* __restrict__ tok, float* __restrict__ ws) {
    __shared__ float sp3[NA * NC];
    __shared__ float tq[NA * NC];
    int sb = blockIdx.x, tid = threadIdx.x;
    const float* proto = ws + OFF_PROTO + sb * NC;
    for (int i = tid; i < NA * NC; i += 256) sp3[i] = proto[i & 255] + tok[i];
    __syncthreads();
    const float4* wq4 = (const float4*)(Wq + (size_t)tid * NC);
    float acc[NA] = {0, 0, 0, 0, 0};
    for (int c4 = 0; c4 < 64; ++c4) {
        float4 w = wq4[c4];
        #pragma unroll
        for (int a = 0; a < NA; ++a) {
            const float* sp = sp3 + a * NC + 4 * c4;
            acc[a] += sp[0] * w.x + sp[1] * w.y + sp[2] * w.z + sp[3] * w.w;
        }
    }
    #pragma unroll
    for (int a = 0; a < NA; ++a) tq[a * NC + tid] = acc[a];
    __syncthreads();
    float acc2[NA] = {0, 0, 0, 0, 0};
    #pragma unroll 4
    for (int co = 0; co < NC; ++co) {
        float w = Wk[(size_t)co * NC + tid];
        #pragma unroll
        for (int a = 0; a < NA; ++a) acc2[a] += tq[a * NC + co] * w;
    }
    float* qko = ws + OFF_QK + sb * NA * NC;
    #pragma unroll
    for (int a = 0; a < NA; ++a) qko[a * NC + tid] = acc2[a];
}

// logit partials: Lpart[ct][sb][a][n] = sum_{c in ct-half} qk[a][c]*feat[c][n]
// grid = 16sb x 8nt x 2ct = 256 blocks; thread owns 2 n.
__global__ __launch_bounds__(256) void k_attnlog(const float* __restrict__ f1, const float* __restrict__ f2,
                                                 float* __restrict__ ws) {
    __shared__ float qk_l[NA * 128];
    int bid = blockIdx.x, tid = threadIdx.x;
    int ct = bid & 1, nt = (bid >> 1) & 7, sb = bid >> 4;
    int s = sb >> 3, b = sb & 7;
    const float* f = s ? f2 : f1;
    const float* qkb = ws + OFF_QK + sb * (NA * NC) + ct * 128;
    for (int i = tid; i < NA * 128; i += 256) qk_l[i] = qkb[(i >> 7) * NC + (i & 127)];
    __syncthreads();
    int h0 = (nt * 512 + tid * 2) >> 1;   // float2 index into 4096-row
    const float2* fb2 = (const float2*)(f + (size_t)b * NC * HW + (size_t)ct * 128 * HW);
    float2 acc[NA] = {};
    #pragma unroll 4
    for (int k = 0; k < 128; ++k) {
        float2 v = fb2[(size_t)k * 2048 + h0];
        #pragma unroll
        for (int a = 0; a < NA; ++a) {
            float w = qk_l[a * 128 + k];
            acc[a].x += w * v.x; acc[a].y += w * v.y;
        }
    }
    float2* Lp = (float2*)(ws + OFF_A + (size_t)(ct * 16 + sb) * NA * HW);
    #pragma unroll
    for (int a = 0; a < NA; ++a) Lp[a * 2048 + h0] = acc[a];
}

// sum partials -> masked softmax -> K=exp(2*attn-2)*mask -> NIT iters -> plan P
__global__ __launch_bounds__(256) void k_sinkhorn(const int* __restrict__ m1, const int* __restrict__ m2,
                                                  float* __restrict__ ws) {
    __shared__ float buf[2][24];
    int sb = blockIdx.x, tid = threadIdx.x;
    int lane = tid & 63, wid = tid >> 6;
    int s = sb >> 3, b = sb & 7;
    const int* m = (s ? m2 : m1) + b * HW;
    const float4* A4 = (const float4*)(ws + OFF_A);
    const int4* mb4 = (const int4*)m;

    unsigned mbits = 0;
    float K[NA][16];
    #pragma unroll
    for (int j = 0; j < 4; ++j) {
        int idx = tid + j * 256;
        int4 mm = mb4[idx];
        if (mm.x == 1) mbits |= 1u << (4 * j + 0);
        if (mm.y == 1) mbits |= 1u << (4 * j + 1);
        if (mm.z == 1) mbits |= 1u << (4 * j + 2);
        if (mm.w == 1) mbits |= 1u << (4 * j + 3);
        #pragma unroll
        for (int a = 0; a < NA; ++a) {
            float4 l0 = A4[(size_t)(sb * NA + a) * 1024 + idx];
            float4 l1 = A4[(size_t)((16 + sb) * NA + a) * 1024 + idx];
            K[a][4 * j + 0] = l0.x + l1.x; K[a][4 * j + 1] = l0.y + l1.y;
            K[a][4 * j + 2] = l0.z + l1.z; K[a][4 * j + 3] = l0.w + l1.w;
        }
    }
    float r[NA];
    #pragma unroll
    for (int a = 0; a < NA; ++a) {
        float mx = -3.0e38f;
        #pragma unroll
        for (int j = 0; j < 16; ++j)
            if ((mbits >> j) & 1) mx = fmaxf(mx, K[a][j]);
        r[a] = mx;
    }
    crossMax4<NA>(r, buf[0], lane, wid);
    float rs6[6];
    #pragma unroll
    for (int a = 0; a < NA; ++a) {
        float sum = 0.f;
        #pragma unroll
        for (int j = 0; j < 16; ++j) {
            float e = ((mbits >> j) & 1) ? expf(K[a][j] - r[a]) : 0.f;
            K[a][j] = e; sum += e;
        }
        rs6[a] = sum;
    }
    rs6[5] = (float)__popc(mbits);
    crossSum4<6>(rs6, buf[1], lane, wid);
    float inv_cnt = frcp(rs6[5]);
    #pragma unroll
    for (int a = 0; a < NA; ++a) {
        float irs = frcp(rs6[a]);
        #pragma unroll
        for (int j = 0; j < 16; ++j) {
            float attn = K[a][j] * irs;
            K[a][j] = ((mbits >> j) & 1) ? expf(2.f * attn - 2.f) : 0.f;
        }
    }
    float u[NA];
    #pragma unroll
    for (int a = 0; a < NA; ++a) u[a] = 0.2f;
    for (int it = 0; it < NIT; ++it) {
        float part[NA] = {0, 0, 0, 0, 0};
        #pragma unroll
        for (int j = 0; j < 16; ++j) {
            float d = 0.f;
            #pragma unroll
            for (int a = 0; a < NA; ++a) d += K[a][j] * u[a];
            float t = inv_cnt * frcp(fmaxf(d, 1e-30f));
            #pragma unroll
            for (int a = 0; a < NA; ++a) part[a] += K[a][j] * t;
        }
        crossSum4<NA>(part, buf[it & 1], lane, wid);
        #pragma unroll
        for (int a = 0; a < NA; ++a) u[a] = 0.2f * frcp(fmaxf(part[a], 1e-30f));
    }
    // write P over the front of region A (only this block's sb-slot; reads done)
    float4* Pb4 = (float4*)(ws + OFF_A) + (size_t)sb * NA * 1024;
    #pragma unroll
    for (int j4 = 0; j4 < 4; ++j4) {
        int idx = tid + j4 * 256;
        float tcol[4];
        #pragma unroll
        for (int k = 0; k < 4; ++k) {
            int j = 4 * j4 + k;
            float d = 0.f;
            #pragma unroll
            for (int a = 0; a < NA; ++a) d += K[a][j] * u[a];
            tcol[k] = inv_cnt * frcp(fmaxf(d, 1e-30f));
        }
        #pragma unroll
        for (int a = 0; a < NA; ++a) {
            float4 o;
            o.x = u[a] * K[a][4 * j4 + 0] * tcol[0];
            o.y = u[a] * K[a][4 * j4 + 1] * tcol[1];
            o.z = u[a] * K[a][4 * j4 + 2] * tcol[2];
            o.w = u[a] * K[a][4 * j4 + 3] * tcol[3];
            Pb4[a * 1024 + idx] = o;
        }
    }
}

// ps[s][b][a][c] = sum_n P[a][n]*feat[c][n]
__global__ __launch_bounds__(256) void k_ps(const float* __restrict__ f1, const float* __restrict__ f2,
                                            float* __restrict__ ws) {
    __shared__ float buf[20];
    int bid = blockIdx.x, tid = threadIdx.x;
    int lane = tid & 63, wid = tid >> 6;
    int s = bid >> 11, b = (bid >> 8) & 7, c = bid & 255;
    const float* f = s ? f2 : f1;
    int sb = s * 8 + b;
    const float4* fb4 = (const float4*)(f + ((size_t)b * NC + c) * HW);
    const float4* Pb4 = (const float4*)(ws + OFF_A) + (size_t)sb * NA * 1024;
    float acc[NA] = {0, 0, 0, 0, 0};
    #pragma unroll
    for (int j = 0; j < 4; ++j) {
        int idx = tid + j * 256;
        float4 v = fb4[idx];
        #pragma unroll
        for (int a = 0; a < NA; ++a) {
            float4 p = Pb4[a * 1024 + idx];
            acc[a] += p.x * v.x + p.y * v.y + p.z * v.z + p.w * v.w;
        }
    }
    crossSum4<NA>(acc, buf, lane, wid);
    if (tid == 0) {
        float* ps = ws + OFF_PS + sb * NA * NC;
        #pragma unroll
        for (int a = 0; a < NA; ++a) ps[a * NC + c] = acc[a];
    }
}

// mem rows 0..9: proto3 + ps @ Wv^T
__global__ __launch_bounds__(256) void k_outproto(const float* __restrict__ Wv, const float* __restrict__ tok,
                                                  float* __restrict__ ws, float* __restrict__ out) {
    __shared__ float sps[NA * NC];
    int sb = blockIdx.x, tid = threadIdx.x;
    int s = sb >> 3, b = sb & 7;
    const float* ps = ws + OFF_PS + sb * NA * NC;
    for (int i = tid; i < NA * NC; i += 256) sps[i] = ps[i];
    __syncthreads();
    const float4* wv4 = (const float4*)(Wv + (size_t)tid * NC);
    float acc[NA] = {0, 0, 0, 0, 0};
    for (int c4 = 0; c4 < 64; ++c4) {
        float4 w = wv4[c4];
        #pragma unroll
        for (int a = 0; a < NA; ++a) {
            const float* sp = sps + a * NC + 4 * c4;
            acc[a] += sp[0] * w.x + sp[1] * w.y + sp[2] * w.z + sp[3] * w.w;
        }
    }
    float p = ws[OFF_PROTO + sb * NC + tid];
    #pragma unroll
    for (int a = 0; a < NA; ++a)
        out[(size_t)b * 20 * NC + (s * NA + a) * NC + tid] = p + tok[a * NC + tid] + acc[a];
}

// attn2 logit partials: part2[ct][ig][b][ii][n] = sum_{c in ct-half} curr[ig*5+ii][c]*qf[c][n]
// grid = 8b x 8nt x 2ct x 2ig = 256 blocks; thread owns 2 n.
__global__ __launch_bounds__(256) void k_attn2log(const float* __restrict__ qf, const float* __restrict__ out,
                                                  float* __restrict__ ws) {
    __shared__ float sc_l[NA * 128];
    int bid = blockIdx.x, tid = threadIdx.x;
    int ig = bid & 1, ct = (bid >> 1) & 1, nt = (bid >> 2) & 7, b = bid >> 5;
    const float* cb = out + (size_t)b * 20 * NC + ig * NA * NC + ct * 128;
    for (int i = tid; i < NA * 128; i += 256) sc_l[i] = cb[(i >> 7) * NC + (i & 127)];
    __syncthreads();
    int h0 = (nt * 512 + tid * 2) >> 1;
    const float2* fb2 = (const float2*)(qf + (size_t)b * NC * HW + (size_t)ct * 128 * HW);
    float2 acc[NA] = {};
    #pragma unroll 4
    for (int k = 0; k < 128; ++k) {
        float2 v = fb2[(size_t)k * 2048 + h0];
        #pragma unroll
        for (int ii = 0; ii < NA; ++ii) {
            float w = sc_l[ii * 128 + k];
            acc[ii].x += w * v.x; acc[ii].y += w * v.y;
        }
    }
    float2* pp = (float2*)(ws + OFF_A + (size_t)(((ct * 2 + ig) * 8 + b) * NA) * HW);
    #pragma unroll
    for (int ii = 0; ii < NA; ++ii) pp[ii * 2048 + h0] = acc[ii];
}

// sum 2 c-half partials, fg from qp inline, *SCL*fg, softmax, store attn*fg
__global__ __launch_bounds__(256) void k_softmax2(const float* __restrict__ qp, float* __restrict__ ws) {
    __shared__ float buf[2][8];
    int row = blockIdx.x, tid = threadIdx.x;
    int lane = tid & 63, wid = tid >> 6;
    int b = row / 10, i = row - b * 10;
    int ig = i / NA, ii = i - ig * NA;
    const float4* pA = (const float4*)(ws + OFF_A) + (size_t)((ig * 8 + b) * NA + ii) * 1024;
    const float4* pB = (const float4*)(ws + OFF_A) + (size_t)(((2 + ig) * 8 + b) * NA + ii) * 1024;
    const float4* qp0 = (const float4*)(qp + (size_t)b * 2 * HW);
    const float4* qp1 = qp0 + 1024;
    float4 lg[4], fgv[4];
    float mx[1] = {-3.0e38f};
    #pragma unroll
    for (int j = 0; j < 4; ++j) {
        int idx = tid + j * 256;
        float4 a = pA[idx], c = pB[idx];
        float4 p0 = qp0[idx], p1 = qp1[idx];
        float4 fg;
        fg.x = 1.f / (1.f + expf(p0.x - p1.x));
        fg.y = 1.f / (1.f + expf(p0.y - p1.y));
        fg.z = 1.f / (1.f + expf(p0.z - p1.z));
        fg.w = 1.f / (1.f + expf(p0.w - p1.w));
        fg.x = fg.x > 0.7f ? 1.f : (fg.x < 0.3f ? 0.f : fg.x);
        fg.y = fg.y > 0.7f ? 1.f : (fg.y < 0.3f ? 0.f : fg.y);
        fg.z = fg.z > 0.7f ? 1.f : (fg.z < 0.3f ? 0.f : fg.z);
        fg.w = fg.w > 0.7f ? 1.f : (fg.w < 0.3f ? 0.f : fg.w);
        fgv[j] = fg;
        lg[j].x = (a.x + c.x) * SCL * fg.x;
        lg[j].y = (a.y + c.y) * SCL * fg.y;
        lg[j].z = (a.z + c.z) * SCL * fg.z;
        lg[j].w = (a.w + c.w) * SCL * fg.w;
        mx[0] = fmaxf(mx[0], fmaxf(fmaxf(lg[j].x, lg[j].y), fmaxf(lg[j].z, lg[j].w)));
    }
    crossMax4<1>(mx, buf[0], lane, wid);
    float sum[1] = {0.f};
    #pragma unroll
    for (int j = 0; j < 4; ++j) {
        lg[j].x = expf(lg[j].x - mx[0]); lg[j].y = expf(lg[j].y - mx[0]);
        lg[j].z = expf(lg[j].z - mx[0]); lg[j].w = expf(lg[j].w - mx[0]);
        sum[0] += lg[j].x + lg[j].y + lg[j].z + lg[j].w;
    }
    crossSum4<1>(sum, buf[1], lane, wid);
    float inv = frcp(sum[0]);
    float4* w24 = (float4*)(ws + OFF_W2) + (size_t)row * 1024;
    #pragma unroll
    for (int j = 0; j < 4; ++j) {
        int idx = tid + j * 256;
        float4 o;
        o.x = lg[j].x * inv * fgv[j].x;
        o.y = lg[j].y * inv * fgv[j].y;
        o.z = lg[j].z * inv * fgv[j].z;
        o.w = lg[j].w * inv * fgv[j].w;
        w24[idx] = o;
    }
}

// mem rows 10..19 = rows 0..9 + attn@qfm ; fused curr_prototype mean.
// grid = 8b x 64 column-groups (4 c each); w2 rows register-cached per pass.
__global__ __launch_bounds__(256) void k_apply2(const float* __restrict__ qf, float* __restrict__ ws,
                                                float* __restrict__ out) {
    __shared__ float buf[4 * 40];
    int bid = blockIdx.x, tid = threadIdx.x;
    int lane = tid & 63, wid = tid >> 6;
    int b = bid >> 6, cg = bid & 63;
    int c0 = cg * 4;
    const float4* qf4 = (const float4*)(qf + (size_t)b * NC * HW);
    const float4* w24 = (const float4*)(ws + OFF_W2) + (size_t)b * 10 * 1024;
    float acc[40] = {};
    #pragma unroll
    for (int j = 0; j < 4; ++j) {
        int idx = tid + j * 256;
        float4 wv[10];
        #pragma unroll
        for (int i = 0; i < 10; ++i) wv[i] = w24[i * 1024 + idx];
        #pragma unroll
        for (int cc = 0; cc < 4; ++cc) {
            float4 v = qf4[(size_t)(c0 + cc) * 1024 + idx];
            #pragma unroll
            for (int i = 0; i < 10; ++i)
                acc[cc * 10 + i] += wv[i].x * v.x + wv[i].y * v.y + wv[i].z * v.z + wv[i].w * v.w;
        }
    }
    crossSum4<40>(acc, buf, lane, wid);
    float* ob = out + (size_t)b * 20 * NC;
    if (tid < 40) {
        int cc = tid / 10, i = tid - cc * 10;
        ob[(10 + i) * NC + c0 + cc] = ob[i * NC + c0 + cc] + acc[tid];
    } else if (tid < 44) {
        int cc = tid - 40;
        float s = 0.f;
        #pragma unroll
        for (int i = 0; i < 10; ++i)
            s += 2.f * ob[i * NC + c0 + cc] + acc[cc * 10 + i];
        out[40960 + b * NC + c0 + cc] = s * 0.05f;
    }
}

extern "C" void kernel_launch(void* const* d_in, const int* in_sizes, int n_in,
                              void* d_out, int out_size, void* d_ws, size_t ws_size,
                              hipStream_t stream) {
    const float* f1  = (const float*)d_in[0];
    const float* f2  = (const float*)d_in[1];
    const int*   m1  = (const int*)d_in[2];
    const int*   m2  = (const int*)d_in[3];
    const float* qf  = (const float*)d_in[4];
    const float* qp  = (const float*)d_in[5];
    const float* Wq  = (const float*)d_in[6];
    const float* Wk  = (const float*)d_in[7];
    const float* Wv  = (const float*)d_in[8];
    const float* tok = (const float*)d_in[9];
    float* out = (float*)d_out;
    float* ws  = (float*)d_ws;

    k_proto<<<4096, 256, 0, stream>>>(f1, f2, m1, m2, ws);
    k_qk<<<16, 256, 0, stream>>>(Wq, Wk, tok, ws);
    k_attnlog<<<256, 256, 0, stream>>>(f1, f2, ws);
    k_sinkhorn<<<16, 256, 0, stream>>>(m1, m2, ws);
    k_ps<<<4096, 256, 0, stream>>>(f1, f2, ws);
    k_outproto<<<16, 256, 0, stream>>>(Wv, tok, ws, out);
    k_attn2log<<<256, 256, 0, stream>>>(qf, out, ws);
    k_softmax2<<<80, 256, 0, stream>>>(qp, ws);
    k_apply2<<<512, 256, 0, stream>>>(qf, ws, out);
}

// Round 5
// 159.637 us; speedup vs baseline: 1.1727x; 1.1727x over previous
//
#include <hip/hip_runtime.h>
#include <hip/hip_bf16.h>
#include <math.h>

#define HW 4096
#define NC 256
#define NB 8
#define NA 5
#define NIT 24
#define SCL 0.0625f

// workspace layout (float offsets).
// Region A (655360 floats) is reused three times, in stream order:
//   1) k_attnlog writes logit partials [ct2][sb16][a5][4096]
//   2) k_sinkhorn sums them, writes plan P [sb16][a5][4096] over the front
//   3) k_attn2log writes attn2 logit partials [ct2][ig2][b8][ii5][4096]
#define OFF_A     0
#define OFF_PROTO 655360                   // 2*8*256
#define OFF_QK    (OFF_PROTO + 4096)       // 2*8*5*256
#define OFF_PS    (OFF_QK + 20480)         // 2*8*5*256
#define OFF_W2    (OFF_PS + 20480)         // 8*10*4096
// total = 1,028,096 floats (4.11 MB)

__device__ inline float frcp(float x) { return __builtin_amdgcn_rcpf(x); }

// ---- DPP wave64 reductions: result valid in lane 63 ----
template<int NV>
__device__ inline void waveSum(float (&v)[NV]) {
    #pragma unroll
    for (int k = 0; k < NV; ++k) {
        float x = v[k]; int t;
        t = __builtin_amdgcn_update_dpp(0, __float_as_int(x), 0x111, 0xf, 0xf, true); x += __int_as_float(t);
        t = __builtin_amdgcn_update_dpp(0, __float_as_int(x), 0x112, 0xf, 0xf, true); x += __int_as_float(t);
        t = __builtin_amdgcn_update_dpp(0, __float_as_int(x), 0x114, 0xf, 0xf, true); x += __int_as_float(t);
        t = __builtin_amdgcn_update_dpp(0, __float_as_int(x), 0x118, 0xf, 0xf, true); x += __int_as_float(t);
        t = __builtin_amdgcn_update_dpp(0, __float_as_int(x), 0x142, 0xf, 0xf, true); x += __int_as_float(t);
        t = __builtin_amdgcn_update_dpp(0, __float_as_int(x), 0x143, 0xf, 0xf, true); x += __int_as_float(t);
        v[k] = x;
    }
}

template<int NV>
__device__ inline void waveMax(float (&v)[NV]) {
    #pragma unroll
    for (int k = 0; k < NV; ++k) {
        float x = v[k]; int t;
        t = __builtin_amdgcn_update_dpp(__float_as_int(x), __float_as_int(x), 0x111, 0xf, 0xf, false); x = fmaxf(x, __int_as_float(t));
        t = __builtin_amdgcn_update_dpp(__float_as_int(x), __float_as_int(x), 0x112, 0xf, 0xf, false); x = fmaxf(x, __int_as_float(t));
        t = __builtin_amdgcn_update_dpp(__float_as_int(x), __float_as_int(x), 0x114, 0xf, 0xf, false); x = fmaxf(x, __int_as_float(t));
        t = __builtin_amdgcn_update_dpp(__float_as_int(x), __float_as_int(x), 0x118, 0xf, 0xf, false); x = fmaxf(x, __int_as_float(t));
        t = __builtin_amdgcn_update_dpp(__float_as_int(x), __float_as_int(x), 0x142, 0xf, 0xf, false); x = fmaxf(x, __int_as_float(t));
        t = __builtin_amdgcn_update_dpp(__float_as_int(x), __float_as_int(x), 0x143, 0xf, 0xf, false); x = fmaxf(x, __int_as_float(t));
        v[k] = x;
    }
}

template<int NV>
__device__ inline void crossSum4(float (&v)[NV], float* buf, int lane, int wid) {
    waveSum<NV>(v);
    if (lane == 63) {
        #pragma unroll
        for (int k = 0; k < NV; ++k) buf[wid * NV + k] = v[k];
    }
    __syncthreads();
    #pragma unroll
    for (int k = 0; k < NV; ++k)
        v[k] = buf[k] + buf[NV + k] + buf[2 * NV + k] + buf[3 * NV + k];
}

template<int NV>
__device__ inline void crossMax4(float (&v)[NV], float* buf, int lane, int wid) {
    waveMax<NV>(v);
    if (lane == 63) {
        #pragma unroll
        for (int k = 0; k < NV; ++k) buf[wid * NV + k] = v[k];
    }
    __syncthreads();
    #pragma unroll
    for (int k = 0; k < NV; ++k)
        v[k] = fmaxf(fmaxf(buf[k], buf[NV + k]), fmaxf(buf[2 * NV + k], buf[3 * NV + k]));
}

// proto[s][b][c] = masked mean over HW (count computed inline)
__global__ __launch_bounds__(256) void k_proto(const float* __restrict__ f1, const float* __restrict__ f2,
                                               const int* __restrict__ m1, const int* __restrict__ m2,
                                               float* __restrict__ ws) {
    __shared__ float buf[8];
    int bid = blockIdx.x, tid = threadIdx.x;
    int lane = tid & 63, wid = tid >> 6;
    int s = bid >> 11, b = (bid >> 8) & 7, c = bid & 255;
    const float* f = s ? f2 : f1;
    const int* m = s ? m2 : m1;
    const float4* fb4 = (const float4*)(f + ((size_t)b * NC + c) * HW);
    const int4* mb4 = (const int4*)(m + b * HW);
    float v2[2] = {0.f, 0.f};
    #pragma unroll
    for (int j = 0; j < 4; ++j) {
        int idx = tid + j * 256;
        float4 v = fb4[idx];
        int4 mm = mb4[idx];
        if (mm.x == 1) { v2[0] += v.x; v2[1] += 1.f; }
        if (mm.y == 1) { v2[0] += v.y; v2[1] += 1.f; }
        if (mm.z == 1) { v2[0] += v.z; v2[1] += 1.f; }
        if (mm.w == 1) { v2[0] += v.w; v2[1] += 1.f; }
    }
    crossSum4<2>(v2, buf, lane, wid);
    if (tid == 0)
        ws[OFF_PROTO + (s * 8 + b) * NC + c] = v2[0] / (v2[1] + 1e-5f);
}

// fused: q = (proto+tok)@Wq^T ; qk = q@Wk
__global__ __launch_bounds__(256) void k_qk(const float* __restrict__ Wq, const float* __restrict__ Wk,
                                            const float* __restrict__ tok, float* __restrict__ ws) {
    __shared__ float sp3[NA * NC];
    __shared__ float tq[NA * NC];
    int sb = blockIdx.x, tid = threadIdx.x;
    const float* proto = ws + OFF_PROTO + sb * NC;
    for (int i = tid; i < NA * NC; i += 256) sp3[i] = proto[i & 255] + tok[i];
    __syncthreads();
    const float4* wq4 = (const float4*)(Wq + (size_t)tid * NC);
    float acc[NA] = {0, 0, 0, 0, 0};
    for (int c4 = 0; c4 < 64; ++c4) {
        float4 w = wq4[c4];
        #pragma unroll
        for (int a = 0; a < NA; ++a) {
            const float* sp = sp3 + a * NC + 4 * c4;
            acc[a] += sp[0] * w.x + sp[1] * w.y + sp[2] * w.z + sp[3] * w.w;
        }
    }
    #pragma unroll
    for (int a = 0; a < NA; ++a) tq[a * NC + tid] = acc[a];
    __syncthreads();
    float acc2[NA] = {0, 0, 0, 0, 0};
    #pragma unroll 4
    for (int co = 0; co < NC; ++co) {
        float w = Wk[(size_t)co * NC + tid];
        #pragma unroll
        for (int a = 0; a < NA; ++a) acc2[a] += tq[a * NC + co] * w;
    }
    float* qko = ws + OFF_QK + sb * NA * NC;
    #pragma unroll
    for (int a = 0; a < NA; ++a) qko[a * NC + tid] = acc2[a];
}

// logit partials: Lpart[ct][sb][a][n] = sum_{c in ct-half} qk[a][c]*feat[c][n]
// grid = 16sb x 8nt x 2ct = 256 blocks; thread owns 2 n.
__global__ __launch_bounds__(256) void k_attnlog(const float* __restrict__ f1, const float* __restrict__ f2,
                                                 float* __restrict__ ws) {
    __shared__ float qk_l[NA * 128];
    int bid = blockIdx.x, tid = threadIdx.x;
    int ct = bid & 1, nt = (bid >> 1) & 7, sb = bid >> 4;
    int s = sb >> 3, b = sb & 7;
    const float* f = s ? f2 : f1;
    const float* qkb = ws + OFF_QK + sb * (NA * NC) + ct * 128;
    for (int i = tid; i < NA * 128; i += 256) qk_l[i] = qkb[(i >> 7) * NC + (i & 127)];
    __syncthreads();
    int h0 = (nt * 512 + tid * 2) >> 1;   // float2 index into 4096-row
    const float2* fb2 = (const float2*)(f + (size_t)b * NC * HW + (size_t)ct * 128 * HW);
    float2 acc[NA] = {};
    #pragma unroll 4
    for (int k = 0; k < 128; ++k) {
        float2 v = fb2[(size_t)k * 2048 + h0];
        #pragma unroll
        for (int a = 0; a < NA; ++a) {
            float w = qk_l[a * 128 + k];
            acc[a].x += w * v.x; acc[a].y += w * v.y;
        }
    }
    float2* Lp = (float2*)(ws + OFF_A + (size_t)(ct * 16 + sb) * NA * HW);
    #pragma unroll
    for (int a = 0; a < NA; ++a) Lp[a * 2048 + h0] = acc[a];
}

// sum partials -> masked softmax -> K=exp(2*attn-2)*mask -> NIT iters -> plan P
__global__ __launch_bounds__(256) void k_sinkhorn(const int* __restrict__ m1, const int* __restrict__ m2,
                                                  float* __restrict__ ws) {
    __shared__ float buf[2][24];
    int sb = blockIdx.x, tid = threadIdx.x;
    int lane = tid & 63, wid = tid >> 6;
    int s = sb >> 3, b = sb & 7;
    const int* m = (s ? m2 : m1) + b * HW;
    const float4* A4 = (const float4*)(ws + OFF_A);
    const int4* mb4 = (const int4*)m;

    unsigned mbits = 0;
    float K[NA][16];
    #pragma unroll
    for (int j = 0; j < 4; ++j) {
        int idx = tid + j * 256;
        int4 mm = mb4[idx];
        if (mm.x == 1) mbits |= 1u << (4 * j + 0);
        if (mm.y == 1) mbits |= 1u << (4 * j + 1);
        if (mm.z == 1) mbits |= 1u << (4 * j + 2);
        if (mm.w == 1) mbits |= 1u << (4 * j + 3);
        #pragma unroll
        for (int a = 0; a < NA; ++a) {
            float4 l0 = A4[(size_t)(sb * NA + a) * 1024 + idx];
            float4 l1 = A4[(size_t)((16 + sb) * NA + a) * 1024 + idx];
            K[a][4 * j + 0] = l0.x + l1.x; K[a][4 * j + 1] = l0.y + l1.y;
            K[a][4 * j + 2] = l0.z + l1.z; K[a][4 * j + 3] = l0.w + l1.w;
        }
    }
    float r[NA];
    #pragma unroll
    for (int a = 0; a < NA; ++a) {
        float mx = -3.0e38f;
        #pragma unroll
        for (int j = 0; j < 16; ++j)
            if ((mbits >> j) & 1) mx = fmaxf(mx, K[a][j]);
        r[a] = mx;
    }
    crossMax4<NA>(r, buf[0], lane, wid);
    float rs6[6];
    #pragma unroll
    for (int a = 0; a < NA; ++a) {
        float sum = 0.f;
        #pragma unroll
        for (int j = 0; j < 16; ++j) {
            float e = ((mbits >> j) & 1) ? expf(K[a][j] - r[a]) : 0.f;
            K[a][j] = e; sum += e;
        }
        rs6[a] = sum;
    }
    rs6[5] = (float)__popc(mbits);
    crossSum4<6>(rs6, buf[1], lane, wid);
    float inv_cnt = frcp(rs6[5]);
    #pragma unroll
    for (int a = 0; a < NA; ++a) {
        float irs = frcp(rs6[a]);
        #pragma unroll
        for (int j = 0; j < 16; ++j) {
            float attn = K[a][j] * irs;
            K[a][j] = ((mbits >> j) & 1) ? expf(2.f * attn - 2.f) : 0.f;
        }
    }
    float u[NA];
    #pragma unroll
    for (int a = 0; a < NA; ++a) u[a] = 0.2f;
    for (int it = 0; it < NIT; ++it) {
        float part[NA] = {0, 0, 0, 0, 0};
        #pragma unroll
        for (int j = 0; j < 16; ++j) {
            float d = 0.f;
            #pragma unroll
            for (int a = 0; a < NA; ++a) d += K[a][j] * u[a];
            float t = inv_cnt * frcp(fmaxf(d, 1e-30f));
            #pragma unroll
            for (int a = 0; a < NA; ++a) part[a] += K[a][j] * t;
        }
        crossSum4<NA>(part, buf[it & 1], lane, wid);
        #pragma unroll
        for (int a = 0; a < NA; ++a) u[a] = 0.2f * frcp(fmaxf(part[a], 1e-30f));
    }
    // write P over the front of region A (only this block's sb-slot; reads done)
    float4* Pb4 = (float4*)(ws + OFF_A) + (size_t)sb * NA * 1024;
    #pragma unroll
    for (int j4 = 0; j4 < 4; ++j4) {
        int idx = tid + j4 * 256;
        float tcol[4];
        #pragma unroll
        for (int k = 0; k < 4; ++k) {
            int j = 4 * j4 + k;
            float d = 0.f;
            #pragma unroll
            for (int a = 0; a < NA; ++a) d += K[a][j] * u[a];
            tcol[k] = inv_cnt * frcp(fmaxf(d, 1e-30f));
        }
        #pragma unroll
        for (int a = 0; a < NA; ++a) {
            float4 o;
            o.x = u[a] * K[a][4 * j4 + 0] * tcol[0];
            o.y = u[a] * K[a][4 * j4 + 1] * tcol[1];
            o.z = u[a] * K[a][4 * j4 + 2] * tcol[2];
            o.w = u[a] * K[a][4 * j4 + 3] * tcol[3];
            Pb4[a * 1024 + idx] = o;
        }
    }
}

// ps[s][b][a][c] = sum_n P[a][n]*feat[c][n]
__global__ __launch_bounds__(256) void k_ps(const float* __restrict__ f1, const float* __restrict__ f2,
                                            float* __restrict__ ws) {
    __shared__ float buf[20];
    int bid = blockIdx.x, tid = threadIdx.x;
    int lane = tid & 63, wid = tid >> 6;
    int s = bid >> 11, b = (bid >> 8) & 7, c = bid & 255;
    const float* f = s ? f2 : f1;
    int sb = s * 8 + b;
    const float4* fb4 = (const float4*)(f + ((size_t)b * NC + c) * HW);
    const float4* Pb4 = (const float4*)(ws + OFF_A) + (size_t)sb * NA * 1024;
    float acc[NA] = {0, 0, 0, 0, 0};
    #pragma unroll
    for (int j = 0; j < 4; ++j) {
        int idx = tid + j * 256;
        float4 v = fb4[idx];
        #pragma unroll
        for (int a = 0; a < NA; ++a) {
            float4 p = Pb4[a * 1024 + idx];
            acc[a] += p.x * v.x + p.y * v.y + p.z * v.z + p.w * v.w;
        }
    }
    crossSum4<NA>(acc, buf, lane, wid);
    if (tid == 0) {
        float* ps = ws + OFF_PS + sb * NA * NC;
        #pragma unroll
        for (int a = 0; a < NA; ++a) ps[a * NC + c] = acc[a];
    }
}

// mem rows 0..9: proto3 + ps @ Wv^T
__global__ __launch_bounds__(256) void k_outproto(const float* __restrict__ Wv, const float* __restrict__ tok,
                                                  float* __restrict__ ws, float* __restrict__ out) {
    __shared__ float sps[NA * NC];
    int sb = blockIdx.x, tid = threadIdx.x;
    int s = sb >> 3, b = sb & 7;
    const float* ps = ws + OFF_PS + sb * NA * NC;
    for (int i = tid; i < NA * NC; i += 256) sps[i] = ps[i];
    __syncthreads();
    const float4* wv4 = (const float4*)(Wv + (size_t)tid * NC);
    float acc[NA] = {0, 0, 0, 0, 0};
    for (int c4 = 0; c4 < 64; ++c4) {
        float4 w = wv4[c4];
        #pragma unroll
        for (int a = 0; a < NA; ++a) {
            const float* sp = sps + a * NC + 4 * c4;
            acc[a] += sp[0] * w.x + sp[1] * w.y + sp[2] * w.z + sp[3] * w.w;
        }
    }
    float p = ws[OFF_PROTO + sb * NC + tid];
    #pragma unroll
    for (int a = 0; a < NA; ++a)
        out[(size_t)b * 20 * NC + (s * NA + a) * NC + tid] = p + tok[a * NC + tid] + acc[a];
}

// attn2 logit partials: part2[ct][ig][b][ii][n] = sum_{c in ct-half} curr[ig*5+ii][c]*qf[c][n]
// grid = 8b x 8nt x 2ct x 2ig = 256 blocks; thread owns 2 n.
__global__ __launch_bounds__(256) void k_attn2log(const float* __restrict__ qf, const float* __restrict__ out,
                                                  float* __restrict__ ws) {
    __shared__ float sc_l[NA * 128];
    int bid = blockIdx.x, tid = threadIdx.x;
    int ig = bid & 1, ct = (bid >> 1) & 1, nt = (bid >> 2) & 7, b = bid >> 5;
    const float* cb = out + (size_t)b * 20 * NC + ig * NA * NC + ct * 128;
    for (int i = tid; i < NA * 128; i += 256) sc_l[i] = cb[(i >> 7) * NC + (i & 127)];
    __syncthreads();
    int h0 = (nt * 512 + tid * 2) >> 1;
    const float2* fb2 = (const float2*)(qf + (size_t)b * NC * HW + (size_t)ct * 128 * HW);
    float2 acc[NA] = {};
    #pragma unroll 4
    for (int k = 0; k < 128; ++k) {
        float2 v = fb2[(size_t)k * 2048 + h0];
        #pragma unroll
        for (int ii = 0; ii < NA; ++ii) {
            float w = sc_l[ii * 128 + k];
            acc[ii].x += w * v.x; acc[ii].y += w * v.y;
        }
    }
    float2* pp = (float2*)(ws + OFF_A + (size_t)(((ct * 2 + ig) * 8 + b) * NA) * HW);
    #pragma unroll
    for (int ii = 0; ii < NA; ++ii) pp[ii * 2048 + h0] = acc[ii];
}

// sum 2 c-half partials, fg from qp inline, *SCL*fg, softmax, store attn*fg
__global__ __launch_bounds__(256) void k_softmax2(const float* __restrict__ qp, float* __restrict__ ws) {
    __shared__ float buf[2][8];
    int row = blockIdx.x, tid = threadIdx.x;
    int lane = tid & 63, wid = tid >> 6;
    int b = row / 10, i = row - b * 10;
    int ig = i / NA, ii = i - ig * NA;
    const float4* pA = (const float4*)(ws + OFF_A) + (size_t)((ig * 8 + b) * NA + ii) * 1024;
    const float4* pB = (const float4*)(ws + OFF_A) + (size_t)(((2 + ig) * 8 + b) * NA + ii) * 1024;
    const float4* qp0 = (const float4*)(qp + (size_t)b * 2 * HW);
    const float4* qp1 = qp0 + 1024;
    float4 lg[4], fgv[4];
    float mx[1] = {-3.0e38f};
    #pragma unroll
    for (int j = 0; j < 4; ++j) {
        int idx = tid + j * 256;
        float4 a = pA[idx], c = pB[idx];
        float4 p0 = qp0[idx], p1 = qp1[idx];
        float4 fg;
        fg.x = 1.f / (1.f + expf(p0.x - p1.x));
        fg.y = 1.f / (1.f + expf(p0.y - p1.y));
        fg.z = 1.f / (1.f + expf(p0.z - p1.z));
        fg.w = 1.f / (1.f + expf(p0.w - p1.w));
        fg.x = fg.x > 0.7f ? 1.f : (fg.x < 0.3f ? 0.f : fg.x);
        fg.y = fg.y > 0.7f ? 1.f : (fg.y < 0.3f ? 0.f : fg.y);
        fg.z = fg.z > 0.7f ? 1.f : (fg.z < 0.3f ? 0.f : fg.z);
        fg.w = fg.w > 0.7f ? 1.f : (fg.w < 0.3f ? 0.f : fg.w);
        fgv[j] = fg;
        lg[j].x = (a.x + c.x) * SCL * fg.x;
        lg[j].y = (a.y + c.y) * SCL * fg.y;
        lg[j].z = (a.z + c.z) * SCL * fg.z;
        lg[j].w = (a.w + c.w) * SCL * fg.w;
        mx[0] = fmaxf(mx[0], fmaxf(fmaxf(lg[j].x, lg[j].y), fmaxf(lg[j].z, lg[j].w)));
    }
    crossMax4<1>(mx, buf[0], lane, wid);
    float sum[1] = {0.f};
    #pragma unroll
    for (int j = 0; j < 4; ++j) {
        lg[j].x = expf(lg[j].x - mx[0]); lg[j].y = expf(lg[j].y - mx[0]);
        lg[j].z = expf(lg[j].z - mx[0]); lg[j].w = expf(lg[j].w - mx[0]);
        sum[0] += lg[j].x + lg[j].y + lg[j].z + lg[j].w;
    }
    crossSum4<1>(sum, buf[1], lane, wid);
    float inv = frcp(sum[0]);
    float4* w24 = (float4*)(ws + OFF_W2) + (size_t)row * 1024;
    #pragma unroll
    for (int j = 0; j < 4; ++j) {
        int idx = tid + j * 256;
        float4 o;
        o.x = lg[j].x * inv * fgv[j].x;
        o.y = lg[j].y * inv * fgv[j].y;
        o.z = lg[j].z * inv * fgv[j].z;
        o.w = lg[j].w * inv * fgv[j].w;
        w24[idx] = o;
    }
}

// mem rows 10..19 = rows 0..9 + attn@qfm ; fused curr_prototype mean.
// grid = 8b x 64 column-groups (4 c each); w2 rows register-cached per pass.
// ALL register-array indexing is compile-time static (no scratch spill).
__global__ __launch_bounds__(256) void k_apply2(const float* __restrict__ qf, float* __restrict__ ws,
                                                float* __restrict__ out) {
    __shared__ float buf[4 * 40];
    int bid = blockIdx.x, tid = threadIdx.x;
    int lane = tid & 63, wid = tid >> 6;
    int b = bid >> 6, cg = bid & 63;
    int c0 = cg * 4;
    const float4* qf4 = (const float4*)(qf + (size_t)b * NC * HW);
    const float4* w24 = (const float4*)(ws + OFF_W2) + (size_t)b * 10 * 1024;
    float acc[40] = {};
    #pragma unroll
    for (int j = 0; j < 4; ++j) {
        int idx = tid + j * 256;
        float4 wv[10];
        #pragma unroll
        for (int i = 0; i < 10; ++i) wv[i] = w24[i * 1024 + idx];
        #pragma unroll
        for (int cc = 0; cc < 4; ++cc) {
            float4 v = qf4[(size_t)(c0 + cc) * 1024 + idx];
            #pragma unroll
            for (int i = 0; i < 10; ++i)
                acc[cc * 10 + i] += wv[i].x * v.x + wv[i].y * v.y + wv[i].z * v.z + wv[i].w * v.w;
        }
    }
    // wave-level reduce (static), partials to LDS, single barrier
    waveSum<40>(acc);
    if (lane == 63) {
        #pragma unroll
        for (int k = 0; k < 40; ++k) buf[wid * 40 + k] = acc[k];
    }
    __syncthreads();
    if (tid == 0) {
        float* ob = out + (size_t)b * 20 * NC;
        #pragma unroll
        for (int cc = 0; cc < 4; ++cc) {
            float s = 0.f;
            #pragma unroll
            for (int i = 0; i < 10; ++i) {
                float d = buf[cc * 10 + i] + buf[40 + cc * 10 + i]
                        + buf[80 + cc * 10 + i] + buf[120 + cc * 10 + i];
                float base = ob[i * NC + c0 + cc];
                float r = base + d;
                ob[(10 + i) * NC + c0 + cc] = r;
                s += base + r;
            }
            out[40960 + b * NC + c0 + cc] = s * 0.05f;
        }
    }
}

extern "C" void kernel_launch(void* const* d_in, const int* in_sizes, int n_in,
                              void* d_out, int out_size, void* d_ws, size_t ws_size,
                              hipStream_t stream) {
    const float* f1  = (const float*)d_in[0];
    const float* f2  = (const float*)d_in[1];
    const int*   m1  = (const int*)d_in[2];
    const int*   m2  = (const int*)d_in[3];
    const float* qf  = (const float*)d_in[4];
    const float* qp  = (const float*)d_in[5];
    const float* Wq  = (const float*)d_in[6];
    const float* Wk  = (const float*)d_in[7];
    const float* Wv  = (const float*)d_in[8];
    const float* tok = (const float*)d_in[9];
    float* out = (float*)d_out;
    float* ws  = (float*)d_ws;

    k_proto<<<4096, 256, 0, stream>>>(f1, f2, m1, m2, ws);
    k_qk<<<16, 256, 0, stream>>>(Wq, Wk, tok, ws);
    k_attnlog<<<256, 256, 0, stream>>>(f1, f2, ws);
    k_sinkhorn<<<16, 256, 0, stream>>>(m1, m2, ws);
    k_ps<<<4096, 256, 0, stream>>>(f1, f2, ws);
    k_outproto<<<16, 256, 0, stream>>>(Wv, tok, ws, out);
    k_attn2log<<<256, 256, 0, stream>>>(qf, out, ws);
    k_softmax2<<<80, 256, 0, stream>>>(qp, ws);
    k_apply2<<<512, 256, 0, stream>>>(qf, ws, out);
}

// Round 6
// 141.254 us; speedup vs baseline: 1.3254x; 1.1301x over previous
//
#include <hip/hip_runtime.h>
#include <hip/hip_bf16.h>
#include <math.h>

#define HW 4096
#define NC 256
#define NB 8
#define NA 5
#define NIT 24
#define SCL 0.0625f

// workspace layout (float offsets).
// Region A (655360 floats) is reused three times, in stream order:
//   1) k_attnlogF writes logit partials [ct2][sb16][a5][4096]
//   2) k_sinkhorn sums them, writes plan P [sb16][a5][4096] over the front
//   3) k_attn2log writes attn2 logit partials [ct2][ig2][b8][ii5][4096]
// OFF_WQK aliases OFF_W2: Wqk lives there from k_stage1 until k_attnlogF
// reads it; k_softmax2 overwrites the region much later.
#define OFF_A     0
#define OFF_PROTO 655360                   // 2*8*256
#define OFF_QK    (OFF_PROTO + 4096)       // (hole, unused)
#define OFF_PS    (OFF_QK + 20480)         // 2*8*5*256
#define OFF_W2    (OFF_PS + 20480)         // 8*10*4096
#define OFF_WQK   OFF_W2                   // 256*256 alias (dead before softmax2)
// total = 1,028,096 floats (4.11 MB)

__device__ inline float frcp(float x) { return __builtin_amdgcn_rcpf(x); }

// ---- DPP wave64 reductions: result valid in lane 63 ----
template<int NV>
__device__ inline void waveSum(float (&v)[NV]) {
    #pragma unroll
    for (int k = 0; k < NV; ++k) {
        float x = v[k]; int t;
        t = __builtin_amdgcn_update_dpp(0, __float_as_int(x), 0x111, 0xf, 0xf, true); x += __int_as_float(t);
        t = __builtin_amdgcn_update_dpp(0, __float_as_int(x), 0x112, 0xf, 0xf, true); x += __int_as_float(t);
        t = __builtin_amdgcn_update_dpp(0, __float_as_int(x), 0x114, 0xf, 0xf, true); x += __int_as_float(t);
        t = __builtin_amdgcn_update_dpp(0, __float_as_int(x), 0x118, 0xf, 0xf, true); x += __int_as_float(t);
        t = __builtin_amdgcn_update_dpp(0, __float_as_int(x), 0x142, 0xf, 0xf, true); x += __int_as_float(t);
        t = __builtin_amdgcn_update_dpp(0, __float_as_int(x), 0x143, 0xf, 0xf, true); x += __int_as_float(t);
        v[k] = x;
    }
}

template<int NV>
__device__ inline void waveMax(float (&v)[NV]) {
    #pragma unroll
    for (int k = 0; k < NV; ++k) {
        float x = v[k]; int t;
        t = __builtin_amdgcn_update_dpp(__float_as_int(x), __float_as_int(x), 0x111, 0xf, 0xf, false); x = fmaxf(x, __int_as_float(t));
        t = __builtin_amdgcn_update_dpp(__float_as_int(x), __float_as_int(x), 0x112, 0xf, 0xf, false); x = fmaxf(x, __int_as_float(t));
        t = __builtin_amdgcn_update_dpp(__float_as_int(x), __float_as_int(x), 0x114, 0xf, 0xf, false); x = fmaxf(x, __int_as_float(t));
        t = __builtin_amdgcn_update_dpp(__float_as_int(x), __float_as_int(x), 0x118, 0xf, 0xf, false); x = fmaxf(x, __int_as_float(t));
        t = __builtin_amdgcn_update_dpp(__float_as_int(x), __float_as_int(x), 0x142, 0xf, 0xf, false); x = fmaxf(x, __int_as_float(t));
        t = __builtin_amdgcn_update_dpp(__float_as_int(x), __float_as_int(x), 0x143, 0xf, 0xf, false); x = fmaxf(x, __int_as_float(t));
        v[k] = x;
    }
}

template<int NV>
__device__ inline void crossSum4(float (&v)[NV], float* buf, int lane, int wid) {
    waveSum<NV>(v);
    if (lane == 63) {
        #pragma unroll
        for (int k = 0; k < NV; ++k) buf[wid * NV + k] = v[k];
    }
    __syncthreads();
    #pragma unroll
    for (int k = 0; k < NV; ++k)
        v[k] = buf[k] + buf[NV + k] + buf[2 * NV + k] + buf[3 * NV + k];
}

template<int NV>
__device__ inline void crossMax4(float (&v)[NV], float* buf, int lane, int wid) {
    waveMax<NV>(v);
    if (lane == 63) {
        #pragma unroll
        for (int k = 0; k < NV; ++k) buf[wid * NV + k] = v[k];
    }
    __syncthreads();
    #pragma unroll
    for (int k = 0; k < NV; ++k)
        v[k] = fmaxf(fmaxf(buf[k], buf[NV + k]), fmaxf(buf[2 * NV + k], buf[3 * NV + k]));
}

// blocks 0..4095: proto (masked mean). blocks 4096..4351: Wqk = Wq^T @ Wk.
__global__ __launch_bounds__(256) void k_stage1(const float* __restrict__ f1, const float* __restrict__ f2,
                                                const int* __restrict__ m1, const int* __restrict__ m2,
                                                const float* __restrict__ Wq, const float* __restrict__ Wk,
                                                float* __restrict__ ws) {
    __shared__ float buf[8];
    int bid = blockIdx.x, tid = threadIdx.x;
    if (bid < 4096) {
        int lane = tid & 63, wid = tid >> 6;
        int s = bid >> 11, b = (bid >> 8) & 7, c = bid & 255;
        const float* f = s ? f2 : f1;
        const int* m = s ? m2 : m1;
        const float4* fb4 = (const float4*)(f + ((size_t)b * NC + c) * HW);
        const int4* mb4 = (const int4*)(m + b * HW);
        float v2[2] = {0.f, 0.f};
        #pragma unroll
        for (int j = 0; j < 4; ++j) {
            int idx = tid + j * 256;
            float4 v = fb4[idx];
            int4 mm = mb4[idx];
            if (mm.x == 1) { v2[0] += v.x; v2[1] += 1.f; }
            if (mm.y == 1) { v2[0] += v.y; v2[1] += 1.f; }
            if (mm.z == 1) { v2[0] += v.z; v2[1] += 1.f; }
            if (mm.w == 1) { v2[0] += v.w; v2[1] += 1.f; }
        }
        crossSum4<2>(v2, buf, lane, wid);
        if (tid == 0)
            ws[OFF_PROTO + (s * 8 + b) * NC + c] = v2[0] / (v2[1] + 1e-5f);
    } else {
        int c1 = bid - 4096;
        float acc = 0.f;
        #pragma unroll 8
        for (int cp = 0; cp < NC; ++cp)
            acc += Wq[(size_t)cp * NC + c1] * Wk[(size_t)cp * NC + tid];
        ws[OFF_WQK + (size_t)c1 * NC + tid] = acc;
    }
}

// phase A: qk-half from (proto+tok)@Wqk; phase B: L partials = qk-half @ feat-half
// grid = 16sb x 8nt x 2ct = 256 blocks; thread owns 2 n in phase B.
__global__ __launch_bounds__(256) void k_attnlogF(const float* __restrict__ f1, const float* __restrict__ f2,
                                                  const float* __restrict__ tok, float* __restrict__ ws) {
    __shared__ float sp3[NA * NC];
    __shared__ float qkp[2][NA * 128];
    __shared__ float qk_l[NA * 128];
    int bid = blockIdx.x, tid = threadIdx.x;
    int ct = bid & 1, nt = (bid >> 1) & 7, sb = bid >> 4;
    int s = sb >> 3, b = sb & 7;
    const float* f = s ? f2 : f1;
    const float* proto = ws + OFF_PROTO + sb * NC;
    for (int i = tid; i < NA * NC; i += 256) sp3[i] = proto[i & 255] + tok[i];
    __syncthreads();
    {   // phase A: threads split the 256-long dot in two halves (ih)
        int cout = tid & 127, ih = tid >> 7;
        const float* wq = ws + OFF_WQK + (size_t)(ih * 128) * NC + ct * 128 + cout;
        const float* sp = sp3 + ih * 128;
        float a0 = 0, a1 = 0, a2 = 0, a3 = 0, a4 = 0;
        #pragma unroll 4
        for (int i = 0; i < 128; ++i) {
            float w = wq[(size_t)i * NC];            // coalesced across cout
            a0 += sp[0 * NC + i] * w; a1 += sp[1 * NC + i] * w; a2 += sp[2 * NC + i] * w;
            a3 += sp[3 * NC + i] * w; a4 += sp[4 * NC + i] * w;
        }
        qkp[ih][0 * 128 + cout] = a0; qkp[ih][1 * 128 + cout] = a1; qkp[ih][2 * 128 + cout] = a2;
        qkp[ih][3 * 128 + cout] = a3; qkp[ih][4 * 128 + cout] = a4;
    }
    __syncthreads();
    for (int i = tid; i < NA * 128; i += 256) qk_l[i] = qkp[0][i] + qkp[1][i];
    __syncthreads();
    // phase B
    int h0 = (nt * 512 + tid * 2) >> 1;   // float2 index into 4096-row
    const float2* fb2 = (const float2*)(f + (size_t)b * NC * HW + (size_t)ct * 128 * HW);
    float2 acc[NA] = {};
    #pragma unroll 4
    for (int k = 0; k < 128; ++k) {
        float2 v = fb2[(size_t)k * 2048 + h0];
        #pragma unroll
        for (int a = 0; a < NA; ++a) {
            float w = qk_l[a * 128 + k];
            acc[a].x += w * v.x; acc[a].y += w * v.y;
        }
    }
    float2* Lp = (float2*)(ws + OFF_A + (size_t)(ct * 16 + sb) * NA * HW);
    #pragma unroll
    for (int a = 0; a < NA; ++a) Lp[a * 2048 + h0] = acc[a];
}

// sum partials -> masked softmax -> K=exp(2*attn-2)*mask -> NIT iters -> plan P
__global__ __launch_bounds__(256) void k_sinkhorn(const int* __restrict__ m1, const int* __restrict__ m2,
                                                  float* __restrict__ ws) {
    __shared__ float buf[2][24];
    int sb = blockIdx.x, tid = threadIdx.x;
    int lane = tid & 63, wid = tid >> 6;
    int s = sb >> 3, b = sb & 7;
    const int* m = (s ? m2 : m1) + b * HW;
    const float4* A4 = (const float4*)(ws + OFF_A);
    const int4* mb4 = (const int4*)m;

    unsigned mbits = 0;
    float K[NA][16];
    #pragma unroll
    for (int j = 0; j < 4; ++j) {
        int idx = tid + j * 256;
        int4 mm = mb4[idx];
        if (mm.x == 1) mbits |= 1u << (4 * j + 0);
        if (mm.y == 1) mbits |= 1u << (4 * j + 1);
        if (mm.z == 1) mbits |= 1u << (4 * j + 2);
        if (mm.w == 1) mbits |= 1u << (4 * j + 3);
        #pragma unroll
        for (int a = 0; a < NA; ++a) {
            float4 l0 = A4[(size_t)(sb * NA + a) * 1024 + idx];
            float4 l1 = A4[(size_t)((16 + sb) * NA + a) * 1024 + idx];
            K[a][4 * j + 0] = l0.x + l1.x; K[a][4 * j + 1] = l0.y + l1.y;
            K[a][4 * j + 2] = l0.z + l1.z; K[a][4 * j + 3] = l0.w + l1.w;
        }
    }
    float r[NA];
    #pragma unroll
    for (int a = 0; a < NA; ++a) {
        float mx = -3.0e38f;
        #pragma unroll
        for (int j = 0; j < 16; ++j)
            if ((mbits >> j) & 1) mx = fmaxf(mx, K[a][j]);
        r[a] = mx;
    }
    crossMax4<NA>(r, buf[0], lane, wid);
    float rs6[6];
    #pragma unroll
    for (int a = 0; a < NA; ++a) {
        float sum = 0.f;
        #pragma unroll
        for (int j = 0; j < 16; ++j) {
            float e = ((mbits >> j) & 1) ? expf(K[a][j] - r[a]) : 0.f;
            K[a][j] = e; sum += e;
        }
        rs6[a] = sum;
    }
    rs6[5] = (float)__popc(mbits);
    crossSum4<6>(rs6, buf[1], lane, wid);
    float inv_cnt = frcp(rs6[5]);
    #pragma unroll
    for (int a = 0; a < NA; ++a) {
        float irs = frcp(rs6[a]);
        #pragma unroll
        for (int j = 0; j < 16; ++j) {
            float attn = K[a][j] * irs;
            K[a][j] = ((mbits >> j) & 1) ? expf(2.f * attn - 2.f) : 0.f;
        }
    }
    float u[NA];
    #pragma unroll
    for (int a = 0; a < NA; ++a) u[a] = 0.2f;
    for (int it = 0; it < NIT; ++it) {
        float part[NA] = {0, 0, 0, 0, 0};
        #pragma unroll
        for (int j = 0; j < 16; ++j) {
            float d = 0.f;
            #pragma unroll
            for (int a = 0; a < NA; ++a) d += K[a][j] * u[a];
            float t = inv_cnt * frcp(fmaxf(d, 1e-30f));
            #pragma unroll
            for (int a = 0; a < NA; ++a) part[a] += K[a][j] * t;
        }
        crossSum4<NA>(part, buf[it & 1], lane, wid);
        #pragma unroll
        for (int a = 0; a < NA; ++a) u[a] = 0.2f * frcp(fmaxf(part[a], 1e-30f));
    }
    float4* Pb4 = (float4*)(ws + OFF_A) + (size_t)sb * NA * 1024;
    #pragma unroll
    for (int j4 = 0; j4 < 4; ++j4) {
        int idx = tid + j4 * 256;
        float tcol[4];
        #pragma unroll
        for (int k = 0; k < 4; ++k) {
            int j = 4 * j4 + k;
            float d = 0.f;
            #pragma unroll
            for (int a = 0; a < NA; ++a) d += K[a][j] * u[a];
            tcol[k] = inv_cnt * frcp(fmaxf(d, 1e-30f));
        }
        #pragma unroll
        for (int a = 0; a < NA; ++a) {
            float4 o;
            o.x = u[a] * K[a][4 * j4 + 0] * tcol[0];
            o.y = u[a] * K[a][4 * j4 + 1] * tcol[1];
            o.z = u[a] * K[a][4 * j4 + 2] * tcol[2];
            o.w = u[a] * K[a][4 * j4 + 3] * tcol[3];
            Pb4[a * 1024 + idx] = o;
        }
    }
}

// ps[s][b][a][c] = sum_n P[a][n]*feat[c][n]
__global__ __launch_bounds__(256) void k_ps(const float* __restrict__ f1, const float* __restrict__ f2,
                                            float* __restrict__ ws) {
    __shared__ float buf[20];
    int bid = blockIdx.x, tid = threadIdx.x;
    int lane = tid & 63, wid = tid >> 6;
    int s = bid >> 11, b = (bid >> 8) & 7, c = bid & 255;
    const float* f = s ? f2 : f1;
    int sb = s * 8 + b;
    const float4* fb4 = (const float4*)(f + ((size_t)b * NC + c) * HW);
    const float4* Pb4 = (const float4*)(ws + OFF_A) + (size_t)sb * NA * 1024;
    float acc[NA] = {0, 0, 0, 0, 0};
    #pragma unroll
    for (int j = 0; j < 4; ++j) {
        int idx = tid + j * 256;
        float4 v = fb4[idx];
        #pragma unroll
        for (int a = 0; a < NA; ++a) {
            float4 p = Pb4[a * 1024 + idx];
            acc[a] += p.x * v.x + p.y * v.y + p.z * v.z + p.w * v.w;
        }
    }
    crossSum4<NA>(acc, buf, lane, wid);
    if (tid == 0) {
        float* ps = ws + OFF_PS + sb * NA * NC;
        #pragma unroll
        for (int a = 0; a < NA; ++a) ps[a * NC + c] = acc[a];
    }
}

// mem rows 0..9: proto3 + ps @ Wv^T.  grid = 16sb x 16 cout-tiles = 256 blocks.
__global__ __launch_bounds__(256) void k_outproto(const float* __restrict__ Wv, const float* __restrict__ tok,
                                                  float* __restrict__ ws, float* __restrict__ out) {
    __shared__ float wv_l[16][NC + 1];   // +1 pad: kills 16-way bank conflict
    __shared__ float ps_l[NA * NC];
    __shared__ float part[80][2];
    int bid = blockIdx.x, tid = threadIdx.x;
    int ctile = bid & 15, sb = bid >> 4;
    int s = sb >> 3, b = sb & 7;
    int c0 = ctile * 16;
    const float4* wv4 = (const float4*)(Wv + (size_t)c0 * NC);
    for (int t = tid; t < 1024; t += 256) {
        int r = t >> 6, q = t & 63;
        float4 v = wv4[(size_t)r * 64 + q];
        wv_l[r][4 * q + 0] = v.x; wv_l[r][4 * q + 1] = v.y;
        wv_l[r][4 * q + 2] = v.z; wv_l[r][4 * q + 3] = v.w;
    }
    const float* ps = ws + OFF_PS + sb * NA * NC;
    for (int i = tid; i < NA * NC; i += 256) ps_l[i] = ps[i];
    __syncthreads();
    if (tid < 160) {
        int o = tid >> 1, seg = tid & 1;
        int a = o >> 4, r = o & 15;
        const float* pa = ps_l + a * NC + seg * 128;
        const float* wr = &wv_l[r][seg * 128];
        float d = 0.f;
        #pragma unroll 8
        for (int i = 0; i < 128; ++i) d += pa[i] * wr[i];
        part[o][seg] = d;
    }
    __syncthreads();
    if (tid < 80) {
        int a = tid >> 4, r = tid & 15;
        int c = c0 + r;
        out[(size_t)b * 20 * NC + (s * NA + a) * NC + c] =
            ws[OFF_PROTO + sb * NC + c] + tok[a * NC + c] + part[tid][0] + part[tid][1];
    }
}

// attn2 logit partials: part2[ct][ig][b][ii][n] = sum_{c in ct-half} curr[ig*5+ii][c]*qf[c][n]
// grid = 8b x 8nt x 2ct x 2ig = 256 blocks; thread owns 2 n.
__global__ __launch_bounds__(256) void k_attn2log(const float* __restrict__ qf, const float* __restrict__ out,
                                                  float* __restrict__ ws) {
    __shared__ float sc_l[NA * 128];
    int bid = blockIdx.x, tid = threadIdx.x;
    int ig = bid & 1, ct = (bid >> 1) & 1, nt = (bid >> 2) & 7, b = bid >> 5;
    const float* cb = out + (size_t)b * 20 * NC + ig * NA * NC + ct * 128;
    for (int i = tid; i < NA * 128; i += 256) sc_l[i] = cb[(i >> 7) * NC + (i & 127)];
    __syncthreads();
    int h0 = (nt * 512 + tid * 2) >> 1;
    const float2* fb2 = (const float2*)(qf + (size_t)b * NC * HW + (size_t)ct * 128 * HW);
    float2 acc[NA] = {};
    #pragma unroll 4
    for (int k = 0; k < 128; ++k) {
        float2 v = fb2[(size_t)k * 2048 + h0];
        #pragma unroll
        for (int ii = 0; ii < NA; ++ii) {
            float w = sc_l[ii * 128 + k];
            acc[ii].x += w * v.x; acc[ii].y += w * v.y;
        }
    }
    float2* pp = (float2*)(ws + OFF_A + (size_t)(((ct * 2 + ig) * 8 + b) * NA) * HW);
    #pragma unroll
    for (int ii = 0; ii < NA; ++ii) pp[ii * 2048 + h0] = acc[ii];
}

// sum 2 c-half partials, fg from qp inline, *SCL*fg, softmax, store attn*fg
__global__ __launch_bounds__(256) void k_softmax2(const float* __restrict__ qp, float* __restrict__ ws) {
    __shared__ float buf[2][8];
    int row = blockIdx.x, tid = threadIdx.x;
    int lane = tid & 63, wid = tid >> 6;
    int b = row / 10, i = row - b * 10;
    int ig = i / NA, ii = i - ig * NA;
    const float4* pA = (const float4*)(ws + OFF_A) + (size_t)((ig * 8 + b) * NA + ii) * 1024;
    const float4* pB = (const float4*)(ws + OFF_A) + (size_t)(((2 + ig) * 8 + b) * NA + ii) * 1024;
    const float4* qp0 = (const float4*)(qp + (size_t)b * 2 * HW);
    const float4* qp1 = qp0 + 1024;
    float4 lg[4], fgv[4];
    float mx[1] = {-3.0e38f};
    #pragma unroll
    for (int j = 0; j < 4; ++j) {
        int idx = tid + j * 256;
        float4 a = pA[idx], c = pB[idx];
        float4 p0 = qp0[idx], p1 = qp1[idx];
        float4 fg;
        fg.x = 1.f / (1.f + expf(p0.x - p1.x));
        fg.y = 1.f / (1.f + expf(p0.y - p1.y));
        fg.z = 1.f / (1.f + expf(p0.z - p1.z));
        fg.w = 1.f / (1.f + expf(p0.w - p1.w));
        fg.x = fg.x > 0.7f ? 1.f : (fg.x < 0.3f ? 0.f : fg.x);
        fg.y = fg.y > 0.7f ? 1.f : (fg.y < 0.3f ? 0.f : fg.y);
        fg.z = fg.z > 0.7f ? 1.f : (fg.z < 0.3f ? 0.f : fg.z);
        fg.w = fg.w > 0.7f ? 1.f : (fg.w < 0.3f ? 0.f : fg.w);
        fgv[j] = fg;
        lg[j].x = (a.x + c.x) * SCL * fg.x;
        lg[j].y = (a.y + c.y) * SCL * fg.y;
        lg[j].z = (a.z + c.z) * SCL * fg.z;
        lg[j].w = (a.w + c.w) * SCL * fg.w;
        mx[0] = fmaxf(mx[0], fmaxf(fmaxf(lg[j].x, lg[j].y), fmaxf(lg[j].z, lg[j].w)));
    }
    crossMax4<1>(mx, buf[0], lane, wid);
    float sum[1] = {0.f};
    #pragma unroll
    for (int j = 0; j < 4; ++j) {
        lg[j].x = expf(lg[j].x - mx[0]); lg[j].y = expf(lg[j].y - mx[0]);
        lg[j].z = expf(lg[j].z - mx[0]); lg[j].w = expf(lg[j].w - mx[0]);
        sum[0] += lg[j].x + lg[j].y + lg[j].z + lg[j].w;
    }
    crossSum4<1>(sum, buf[1], lane, wid);
    float inv = frcp(sum[0]);
    float4* w24 = (float4*)(ws + OFF_W2) + (size_t)row * 1024;
    #pragma unroll
    for (int j = 0; j < 4; ++j) {
        int idx = tid + j * 256;
        float4 o;
        o.x = lg[j].x * inv * fgv[j].x;
        o.y = lg[j].y * inv * fgv[j].y;
        o.z = lg[j].z * inv * fgv[j].z;
        o.w = lg[j].w * inv * fgv[j].w;
        w24[idx] = o;
    }
}

// mem rows 10..19 = rows 0..9 + attn@qfm ; fused curr_prototype mean.
// grid = 8b x 64 column-groups (4 c each); all reg-array indexing static.
__global__ __launch_bounds__(256) void k_apply2(const float* __restrict__ qf, float* __restrict__ ws,
                                                float* __restrict__ out) {
    __shared__ float buf[4 * 40];
    int bid = blockIdx.x, tid = threadIdx.x;
    int lane = tid & 63, wid = tid >> 6;
    int b = bid >> 6, cg = bid & 63;
    int c0 = cg * 4;
    const float4* qf4 = (const float4*)(qf + (size_t)b * NC * HW);
    const float4* w24 = (const float4*)(ws + OFF_W2) + (size_t)b * 10 * 1024;
    float acc[40] = {};
    #pragma unroll
    for (int j = 0; j < 4; ++j) {
        int idx = tid + j * 256;
        float4 wv[10];
        #pragma unroll
        for (int i = 0; i < 10; ++i) wv[i] = w24[i * 1024 + idx];
        #pragma unroll
        for (int cc = 0; cc < 4; ++cc) {
            float4 v = qf4[(size_t)(c0 + cc) * 1024 + idx];
            #pragma unroll
            for (int i = 0; i < 10; ++i)
                acc[cc * 10 + i] += wv[i].x * v.x + wv[i].y * v.y + wv[i].z * v.z + wv[i].w * v.w;
        }
    }
    waveSum<40>(acc);
    if (lane == 63) {
        #pragma unroll
        for (int k = 0; k < 40; ++k) buf[wid * 40 + k] = acc[k];
    }
    __syncthreads();
    if (tid == 0) {
        float* ob = out + (size_t)b * 20 * NC;
        #pragma unroll
        for (int cc = 0; cc < 4; ++cc) {
            float s = 0.f;
            #pragma unroll
            for (int i = 0; i < 10; ++i) {
                float d = buf[cc * 10 + i] + buf[40 + cc * 10 + i]
                        + buf[80 + cc * 10 + i] + buf[120 + cc * 10 + i];
                float base = ob[i * NC + c0 + cc];
                float r = base + d;
                ob[(10 + i) * NC + c0 + cc] = r;
                s += base + r;
            }
            out[40960 + b * NC + c0 + cc] = s * 0.05f;
        }
    }
}

extern "C" void kernel_launch(void* const* d_in, const int* in_sizes, int n_in,
                              void* d_out, int out_size, void* d_ws, size_t ws_size,
                              hipStream_t stream) {
    const float* f1  = (const float*)d_in[0];
    const float* f2  = (const float*)d_in[1];
    const int*   m1  = (const int*)d_in[2];
    const int*   m2  = (const int*)d_in[3];
    const float* qf  = (const float*)d_in[4];
    const float* qp  = (const float*)d_in[5];
    const float* Wq  = (const float*)d_in[6];
    const float* Wk  = (const float*)d_in[7];
    const float* Wv  = (const float*)d_in[8];
    const float* tok = (const float*)d_in[9];
    float* out = (float*)d_out;
    float* ws  = (float*)d_ws;

    k_stage1<<<4352, 256, 0, stream>>>(f1, f2, m1, m2, Wq, Wk, ws);
    k_attnlogF<<<256, 256, 0, stream>>>(f1, f2, tok, ws);
    k_sinkhorn<<<16, 256, 0, stream>>>(m1, m2, ws);
    k_ps<<<4096, 256, 0, stream>>>(f1, f2, ws);
    k_outproto<<<256, 256, 0, stream>>>(Wv, tok, ws, out);
    k_attn2log<<<256, 256, 0, stream>>>(qf, out, ws);
    k_softmax2<<<80, 256, 0, stream>>>(qp, ws);
    k_apply2<<<512, 256, 0, stream>>>(qf, ws, out);
}